// Round 13
// baseline (119.124 us; speedup 1.0000x reference)
//
#include <hip/hip_runtime.h>
#include <math.h>

// Tropical max/min-plus pseudo-matmul — DIAGNOSTIC (reps=6).
// out[b,u] = max_f(x[b,f] + w[f,u]) for u<128, min_f otherwise.
//
// R6..R12 all land ~23-28us regardless of occupancy/U/BR/pipelining; only one
// clean-counter row exists (R2) and the R10 diagnostic (reps=2, 34us) missed
// the ~41us top-5 cutoff. This round: R12's exact pipelined structure with
// reps=6 idempotent passes (max(a,a)=a -> bit-identical output; runtime trip
// count + memory clobber block CSE). Kernel ~23+5*loop -> lands in top-5 and
// yields VALUBusy/Occupancy/FETCH/conflict/VGPR; the timing delta separately
// measures R12's marginal loop cost vs R9's measured 10.7us/pass.

#define FEAT  512
#define UNITS 256
#define BR    8          // rows per block
#define KW    64         // k per wave
#define NW    8          // waves per block
#define NQ    (KW / 4)   // 16 quads per wave

__device__ __forceinline__ float max3(float a, float b, float c) {
    return fmaxf(fmaxf(a, b), c);   // v_max3_f32
}

__device__ __forceinline__ void load_xquad(const float* __restrict__ lds, int kb, int q,
                                           float4* __restrict__ xb) {
    #pragma unroll
    for (int r = 0; r < BR; ++r)
        xb[r] = *(const float4*)&lds[r * FEAT + kb + q * 4];
}

__device__ __forceinline__ void load_wquad(const float* __restrict__ wp, int q,
                                           float4* __restrict__ wb) {
    #pragma unroll
    for (int k = 0; k < 4; ++k)
        wb[k] = *(const float4*)(wp + (size_t)(q * 4 + k) * UNITS);
}

__device__ __forceinline__ void compute_quad(const float4* __restrict__ xb,
                                             const float4* __restrict__ wq,
                                             float sgn, float4* __restrict__ acc) {
    const float4 w0 = make_float4(wq[0].x*sgn, wq[0].y*sgn, wq[0].z*sgn, wq[0].w*sgn);
    const float4 w1 = make_float4(wq[1].x*sgn, wq[1].y*sgn, wq[1].z*sgn, wq[1].w*sgn);
    const float4 w2 = make_float4(wq[2].x*sgn, wq[2].y*sgn, wq[2].z*sgn, wq[2].w*sgn);
    const float4 w3 = make_float4(wq[3].x*sgn, wq[3].y*sgn, wq[3].z*sgn, wq[3].w*sgn);
    #pragma unroll
    for (int r = 0; r < BR; ++r) {
        const float4 a = xb[r];
        float4 A = acc[r];
        A.x = max3(A.x, fmaf(a.x, sgn, w0.x), fmaf(a.y, sgn, w1.x));
        A.x = max3(A.x, fmaf(a.z, sgn, w2.x), fmaf(a.w, sgn, w3.x));
        A.y = max3(A.y, fmaf(a.x, sgn, w0.y), fmaf(a.y, sgn, w1.y));
        A.y = max3(A.y, fmaf(a.z, sgn, w2.y), fmaf(a.w, sgn, w3.y));
        A.z = max3(A.z, fmaf(a.x, sgn, w0.z), fmaf(a.y, sgn, w1.z));
        A.z = max3(A.z, fmaf(a.z, sgn, w2.z), fmaf(a.w, sgn, w3.z));
        A.w = max3(A.w, fmaf(a.x, sgn, w0.w), fmaf(a.y, sgn, w1.w));
        A.w = max3(A.w, fmaf(a.z, sgn, w2.w), fmaf(a.w, sgn, w3.w));
        acc[r] = A;
    }
}

__global__ __launch_bounds__(512) void tropical_kernel(const float* __restrict__ x,
                                                       const float* __restrict__ w,
                                                       float* __restrict__ out,
                                                       int reps) {
    __shared__ float lds[NW * BR * UNITS];   // 64 KB; x tile in first 16 KB
    const int tid  = threadIdx.x;
    const int lane = tid & 63;
    const int wv   = __builtin_amdgcn_readfirstlane(tid >> 6);  // 0..7
    const int u0   = lane * 4;                                  // 0..252
    const float sgn = (lane < 32) ? 1.0f : -1.0f;               // min half negated
    const int row0 = blockIdx.x * BR;
    const int kb   = wv * KW;

    // ---- stage x tile (8 rows x 512 = 16 KB), two float4 per thread ----
    {
        const float4* src = (const float4*)(x + (size_t)row0 * FEAT);
        ((float4*)lds)[tid]       = src[tid];
        ((float4*)lds)[tid + 512] = src[tid + 512];
    }

    const float* wp = w + (size_t)kb * UNITS + u0;

    float4 acc[BR];
    #pragma unroll
    for (int r = 0; r < BR; ++r)
        acc[r] = make_float4(-__builtin_inff(), -__builtin_inff(),
                             -__builtin_inff(), -__builtin_inff());

    __syncthreads();   // x tile visible

    float4 xA[BR], xB[BR], wA[4], wB[4];

    // DIAGNOSTIC: reps idempotent passes; output bit-identical to one pass.
    #pragma unroll 1
    for (int rep = 0; rep < reps; ++rep) {
        load_wquad(wp, 0, wA);
        load_xquad(lds, kb, 0, xA);
        #pragma unroll 1
        for (int q = 0; q < NQ; q += 2) {
            load_wquad(wp, q + 1, wB);
            load_xquad(lds, kb, q + 1, xB);
            compute_quad(xA, wA, sgn, acc);
            if (q + 2 < NQ) {
                load_wquad(wp, q + 2, wA);
                load_xquad(lds, kb, q + 2, xA);
            }
            compute_quad(xB, wB, sgn, acc);
        }
        __asm__ __volatile__("" ::: "memory");   // block cross-rep CSE/hoist
    }

    // ---- combine 8 k-partials via LDS (reuses x region; 64 KB) ----
    __syncthreads();   // all waves done reading x tile
    #pragma unroll
    for (int r = 0; r < BR; ++r)
        *(float4*)&lds[((wv * BR + r) * UNITS) + u0] = acc[r];
    __syncthreads();

    // thread -> float4 of output: r = tid>>6 (0..7), units uo..uo+3
    const int r  = tid >> 6;
    const int uo = (tid & 63) * 4;
    float4 v = *(const float4*)&lds[(0 * BR + r) * UNITS + uo];
    #pragma unroll
    for (int j = 1; j < NW; ++j) {
        const float4 p = *(const float4*)&lds[(j * BR + r) * UNITS + uo];
        v.x = fmaxf(v.x, p.x);
        v.y = fmaxf(v.y, p.y);
        v.z = fmaxf(v.z, p.z);
        v.w = fmaxf(v.w, p.w);
    }
    const float so = (uo < 128) ? 1.0f : -1.0f;    // undo negation for min half
    *(float4*)&out[(size_t)(row0 + r) * UNITS + uo] =
        make_float4(v.x * so, v.y * so, v.z * so, v.w * so);
}

extern "C" void kernel_launch(void* const* d_in, const int* in_sizes, int n_in,
                              void* d_out, int out_size, void* d_ws, size_t ws_size,
                              hipStream_t stream) {
    const float* x = (const float*)d_in[0];   // (2048, 512)
    const float* w = (const float*)d_in[1];   // (512, 256)
    float* out = (float*)d_out;               // (2048, 256)

    // 256 blocks x 8 waves = 2048 waves = 2/SIMD, 1 block/CU.
    // reps=6: idempotent multi-pass purely to surface kernel counters in the
    // rocprof top-5 (same work every call -> graph-capture safe).
    tropical_kernel<<<dim3(2048 / BR), dim3(512), 0, stream>>>(x, w, out, 6);
}

// Round 14
// 69.502 us; speedup vs baseline: 1.7140x; 1.7140x over previous
//
#include <hip/hip_runtime.h>
#include <math.h>

// Tropical max/min-plus pseudo-matmul.
// out[b,u] = max_f(x[b,f] + w[f,u]) for u<128, min_f otherwise.
//
// R13 MEASURED: VALUBusy 97.5%, VGPR 104, FETCH 4.1MB, conflicts 0, loop
// 10.7us/pass — purely VALU-issue-bound; occupancy/BR/U/pipelining were all
// dead levers. R14: packed-math diet. v_pk_add_f32 (2 adds/instr) with
// op_sel broadcast of the x scalar (no dup movs; pairs pack over the lane's
// 2 adjacent units), merged by explicit v_max3_f32: 1.0 instr/MAC vs 1.63.
// fma gone -> per-lane sign needs +-x: dual x-tile in LDS (x, -x); lanes>=32
// read the negated tile (2-address broadcast = 2-way = free). w sign folded
// by 16 muls/quad. All ops exact -> absmax 0. Structure else = R12 (BR=8,
// U=4, NW=8, KW=64, 256 blocks = 1/CU, A/B pipelined quads).

#define FEAT  512
#define UNITS 256
#define BR    8          // rows per block
#define KW    64         // k per wave
#define NW    8          // waves per block
#define NQ    (KW / 4)   // 16 quads per wave
#define XNEG  4096       // float offset of negated x tile in LDS

// s = (x_bcast + w.lo, x_bcast + w.hi), x taken from x2's LOW half
__device__ __forceinline__ float2 pk_add_b0(float2 x2, float2 w2) {
    float2 d;
    asm("v_pk_add_f32 %0, %1, %2 op_sel:[0,0] op_sel_hi:[0,1]"
        : "=v"(d) : "v"(x2), "v"(w2));
    return d;
}
// same, x taken from x2's HIGH half
__device__ __forceinline__ float2 pk_add_b1(float2 x2, float2 w2) {
    float2 d;
    asm("v_pk_add_f32 %0, %1, %2 op_sel:[1,0] op_sel_hi:[1,1]"
        : "=v"(d) : "v"(x2), "v"(w2));
    return d;
}
__device__ __forceinline__ float max3a(float a, float b, float c) {
    float d;
    asm("v_max3_f32 %0, %1, %2, %3" : "=v"(d) : "v"(a), "v"(b), "v"(c));
    return d;
}

__device__ __forceinline__ void load_xquad(const float* __restrict__ xb_lds,
                                           int kb, int q, float4* __restrict__ xb) {
    #pragma unroll
    for (int r = 0; r < BR; ++r)
        xb[r] = *(const float4*)&xb_lds[r * FEAT + kb + q * 4];
}

__device__ __forceinline__ void load_wquad(const float* __restrict__ wp, int q,
                                           float4* __restrict__ wb) {
    #pragma unroll
    for (int k = 0; k < 4; ++k)
        wb[k] = *(const float4*)(wp + (size_t)(q * 4 + k) * UNITS);
}

__device__ __forceinline__ void compute_quad(const float4* __restrict__ xb,
                                             const float4* __restrict__ wq,
                                             float sgn, float4* __restrict__ acc) {
    // fold per-lane sign into w once per quad (16 muls / 128 MACs)
    float4 w0 = wq[0], w1 = wq[1], w2 = wq[2], w3 = wq[3];
    w0.x *= sgn; w0.y *= sgn; w0.z *= sgn; w0.w *= sgn;
    w1.x *= sgn; w1.y *= sgn; w1.z *= sgn; w1.w *= sgn;
    w2.x *= sgn; w2.y *= sgn; w2.z *= sgn; w2.w *= sgn;
    w3.x *= sgn; w3.y *= sgn; w3.z *= sgn; w3.w *= sgn;
    const float2 w0lo = make_float2(w0.x, w0.y), w0hi = make_float2(w0.z, w0.w);
    const float2 w1lo = make_float2(w1.x, w1.y), w1hi = make_float2(w1.z, w1.w);
    const float2 w2lo = make_float2(w2.x, w2.y), w2hi = make_float2(w2.z, w2.w);
    const float2 w3lo = make_float2(w3.x, w3.y), w3hi = make_float2(w3.z, w3.w);
    #pragma unroll
    for (int r = 0; r < BR; ++r) {
        const float2 alo = make_float2(xb[r].x, xb[r].y);
        const float2 ahi = make_float2(xb[r].z, xb[r].w);
        float4 A = acc[r];
        // units u0,u1
        const float2 s0 = pk_add_b0(alo, w0lo);   // (x0+wk0u0, x0+wk0u1)
        const float2 s1 = pk_add_b1(alo, w1lo);   // x1+wk1
        const float2 s2 = pk_add_b0(ahi, w2lo);   // x2+wk2
        const float2 s3 = pk_add_b1(ahi, w3lo);   // x3+wk3
        A.x = max3a(A.x, s0.x, s1.x);
        A.x = max3a(A.x, s2.x, s3.x);
        A.y = max3a(A.y, s0.y, s1.y);
        A.y = max3a(A.y, s2.y, s3.y);
        // units u2,u3
        const float2 t0 = pk_add_b0(alo, w0hi);
        const float2 t1 = pk_add_b1(alo, w1hi);
        const float2 t2 = pk_add_b0(ahi, w2hi);
        const float2 t3 = pk_add_b1(ahi, w3hi);
        A.z = max3a(A.z, t0.x, t1.x);
        A.z = max3a(A.z, t2.x, t3.x);
        A.w = max3a(A.w, t0.y, t1.y);
        A.w = max3a(A.w, t2.y, t3.y);
        acc[r] = A;
    }
}

__global__ __launch_bounds__(512) void tropical_kernel(const float* __restrict__ x,
                                                       const float* __restrict__ w,
                                                       float* __restrict__ out) {
    __shared__ float lds[NW * BR * UNITS];   // 64 KB; x tiles in first 32 KB
    const int tid  = threadIdx.x;
    const int lane = tid & 63;
    const int wv   = __builtin_amdgcn_readfirstlane(tid >> 6);  // 0..7
    const int u0   = lane * 4;                                  // 0..252
    const float sgn = (lane < 32) ? 1.0f : -1.0f;               // min half negated
    const int row0 = blockIdx.x * BR;
    const int kb   = wv * KW;

    // ---- stage dual x tile: x in [0,4096), -x in [4096,8192) floats ----
    {
        const float4* src = (const float4*)(x + (size_t)row0 * FEAT);
        const float4 v0 = src[tid];
        const float4 v1 = src[tid + 512];
        ((float4*)lds)[tid]       = v0;
        ((float4*)lds)[tid + 512] = v1;
        ((float4*)(lds + XNEG))[tid]       = make_float4(-v0.x, -v0.y, -v0.z, -v0.w);
        ((float4*)(lds + XNEG))[tid + 512] = make_float4(-v1.x, -v1.y, -v1.z, -v1.w);
    }

    const float* wp = w + (size_t)kb * UNITS + u0;
    const float* xb_lds = lds + ((lane >= 32) ? XNEG : 0);   // per-lane signed tile

    float4 acc[BR];
    #pragma unroll
    for (int r = 0; r < BR; ++r)
        acc[r] = make_float4(-__builtin_inff(), -__builtin_inff(),
                             -__builtin_inff(), -__builtin_inff());

    float4 xA[BR], xB[BR], wA[4], wB[4];
    load_wquad(wp, 0, wA);

    __syncthreads();   // x tiles visible
    load_xquad(xb_lds, kb, 0, xA);

    #pragma unroll 1
    for (int q = 0; q < NQ; q += 2) {
        load_wquad(wp, q + 1, wB);
        load_xquad(xb_lds, kb, q + 1, xB);
        compute_quad(xA, wA, sgn, acc);
        if (q + 2 < NQ) {
            load_wquad(wp, q + 2, wA);
            load_xquad(xb_lds, kb, q + 2, xA);
        }
        compute_quad(xB, wB, sgn, acc);
    }

    // ---- combine 8 k-partials via LDS (overwrites x region; 64 KB) ----
    __syncthreads();   // all waves done reading x tiles
    #pragma unroll
    for (int r = 0; r < BR; ++r)
        *(float4*)&lds[((wv * BR + r) * UNITS) + u0] = acc[r];
    __syncthreads();

    // thread -> float4 of output: r = tid>>6 (0..7), units uo..uo+3
    const int r  = tid >> 6;
    const int uo = (tid & 63) * 4;
    float4 v = *(const float4*)&lds[(0 * BR + r) * UNITS + uo];
    #pragma unroll
    for (int j = 1; j < NW; ++j) {
        const float4 p = *(const float4*)&lds[(j * BR + r) * UNITS + uo];
        v.x = fmaxf(v.x, p.x);
        v.y = fmaxf(v.y, p.y);
        v.z = fmaxf(v.z, p.z);
        v.w = fmaxf(v.w, p.w);
    }
    const float so = (uo < 128) ? 1.0f : -1.0f;    // undo negation for min half
    *(float4*)&out[(size_t)(row0 + r) * UNITS + uo] =
        make_float4(v.x * so, v.y * so, v.z * so, v.w * so);
}

extern "C" void kernel_launch(void* const* d_in, const int* in_sizes, int n_in,
                              void* d_out, int out_size, void* d_ws, size_t ws_size,
                              hipStream_t stream) {
    const float* x = (const float*)d_in[0];   // (2048, 512)
    const float* w = (const float*)d_in[1];   // (512, 256)
    float* out = (float*)d_out;               // (2048, 256)

    // 256 blocks x 8 waves = 2048 waves = 2/SIMD, 1 block/CU
    tropical_kernel<<<dim3(2048 / BR), dim3(512), 0, stream>>>(x, w, out);
}